// Round 4
// baseline (489.948 us; speedup 1.0000x reference)
//
#include <hip/hip_runtime.h>
#include <math.h>

#define BLOCK   384
#define I_CAPS  1152
#define O_CAPS  32
#define D_DIM   16
#define RPT     12         // quarter-rows (float4 chunks) per thread
#define K_SEL   922        // ceil(0.8 * 1152)
#define NWAVES  6

// intra-quad xor shuffles as DPP (VALU pipe, not LDS)
__device__ __forceinline__ float dpp_xor1(float x) {
    return __int_as_float(__builtin_amdgcn_mov_dpp(__float_as_int(x), 0xB1, 0xF, 0xF, true));
}
__device__ __forceinline__ float dpp_xor2(float x) {
    return __int_as_float(__builtin_amdgcn_mov_dpp(__float_as_int(x), 0x4E, 0xF, 0xF, true));
}

__global__ __launch_bounds__(BLOCK, 5)
void subset_routing_kernel(const float* __restrict__ u, float* __restrict__ out) {
    __shared__ int   sh_hist[NWAVES][256];   // per-wave histograms: wave-local atomics
    __shared__ float sh_num[NWAVES][16];
    __shared__ float sh_den[NWAVES];
    __shared__ float sh_v[D_DIM];
    __shared__ unsigned sh_prefix;
    __shared__ int   sh_k;

    const int t    = threadIdx.x;
    const int lane = t & 63;
    const int wave = t >> 6;
    const int c    = t & 3;    // d-chunk (quad lane)
    const int s    = t >> 2;   // row-subgroup 0..95

    // block -> (b,o): pair (b,2j)/(b,2j+1) on same XCD so 128B lines are shared
    int X = blockIdx.x;
    int r8 = X & 7, mm = (X >> 3) & 1, q8 = X >> 4;
    int p  = q8 * 8 + r8;
    int b  = p >> 4;
    int o  = ((p & 15) << 1) | mm;

    const float* base = u + (((size_t)b * I_CAPS) * O_CAPS + (size_t)o) * D_DIM + c * 4;

    // coalesced: per wave-load, 16 rows x 64B contiguous chunks
    float4 q[RPT];
    #pragma unroll
    for (int r = 0; r < RPT; ++r)
        q[r] = *(const float4*)(base + (size_t)(r * 96 + s) * (O_CAPS * D_DIM));

    // ---- phase A: norms + weighted sums (norms via quad DPP xor) ----
    float ax = 0.f, ay = 0.f, az = 0.f, aw = 0.f, dn = 0.f;
    #pragma unroll
    for (int r = 0; r < RPT; ++r) {
        float ss = q[r].x*q[r].x + q[r].y*q[r].y + q[r].z*q[r].z + q[r].w*q[r].w;
        ss += dpp_xor1(ss); ss += dpp_xor2(ss);     // full row ||u||^2 in all 4 lanes
        float n = sqrtf(ss);
        ax += q[r].x * n; ay += q[r].y * n; az += q[r].z * n; aw += q[r].w * n;
        dn += n;                                    // counted x4 across quad; /4 later
    }
    #pragma unroll
    for (int off = 4; off < 64; off <<= 1) {        // reduce over same-c lanes
        ax += __shfl_down(ax, off); ay += __shfl_down(ay, off);
        az += __shfl_down(az, off); aw += __shfl_down(aw, off);
        dn += __shfl_down(dn, off);
    }
    dn += dpp_xor1(dn); dn += dpp_xor2(dn);         // fold quad for den
    if (lane < 4) {
        float* dst = &sh_num[wave][lane * 4];
        dst[0] = ax; dst[1] = ay; dst[2] = az; dst[3] = aw;
    }
    if (lane == 0) sh_den[wave] = dn;
    __syncthreads();
    if (t < D_DIM) {
        float nm = 0.f, dd = 0.f;
        #pragma unroll
        for (int w = 0; w < NWAVES; ++w) { nm += sh_num[w][t]; dd += sh_den[w]; }
        sh_v[t] = nm / (dd * 0.25f);
    }
    __syncthreads();
    float4 v4 = make_float4(sh_v[c*4+0], sh_v[c*4+1], sh_v[c*4+2], sh_v[c*4+3]);

    // ---- keys: loss = -<v,u_i>, order-preserving uint (all quad lanes hold it) ----
    unsigned key[RPT];
    #pragma unroll
    for (int r = 0; r < RPT; ++r) {
        float dl = v4.x*q[r].x + v4.y*q[r].y + v4.z*q[r].z + v4.w*q[r].w;
        dl += dpp_xor1(dl); dl += dpp_xor2(dl);
        unsigned bits = __float_as_uint(-dl);
        key[r] = bits ^ (((unsigned)((int)bits >> 31)) | 0x80000000u);
    }

    // de-replicated: quad lane c owns keys [3c, 3c+3) -> exactly 1152 hist adds/round
    const unsigned mk0 = key[c*3+0], mk1 = key[c*3+1], mk2 = key[c*3+2];
    int* myhist = sh_hist[wave];

    // ---- exact k-th smallest: 4-round MSD radix select, per-wave hists ----
    unsigned prefix = 0u;
    int kk = K_SEL;
    #pragma unroll
    for (int shift = 24; shift >= 0; shift -= 8) {
        // wave-local zero (no cross-wave dependency -> no barrier needed here)
        *(int4*)&myhist[lane * 4] = make_int4(0, 0, 0, 0);
        unsigned maskAbove = (shift == 24) ? 0u : (0xFFFFFFFFu << (shift + 8));
        if ((mk0 & maskAbove) == prefix) atomicAdd(&myhist[(mk0 >> shift) & 255u], 1);
        if ((mk1 & maskAbove) == prefix) atomicAdd(&myhist[(mk1 >> shift) & 255u], 1);
        if ((mk2 & maskAbove) == prefix) atomicAdd(&myhist[(mk2 >> shift) & 255u], 1);
        __syncthreads();
        if (wave == 0) {
            int c0 = 0, c1 = 0, c2 = 0, c3 = 0;
            #pragma unroll
            for (int w = 0; w < NWAVES; ++w) {
                int4 h = *(int4*)&sh_hist[w][lane * 4];
                c0 += h.x; c1 += h.y; c2 += h.z; c3 += h.w;
            }
            int sm = c0 + c1 + c2 + c3;
            int cum = sm;
            #pragma unroll
            for (int off = 1; off < 64; off <<= 1) {
                int vsh = __shfl_up(cum, off);
                if (lane >= off) cum += vsh;
            }
            int cumprev = cum - sm;
            bool has = (cumprev < kk) && (cum >= kk);
            unsigned long long ball = __ballot(has);
            int win = __ffsll(ball) - 1;
            if (lane == win) {
                int kr = kk - cumprev;
                int digit = 0;
                if (kr > c0) { kr -= c0; digit = 1;
                    if (kr > c1) { kr -= c1; digit = 2;
                        if (kr > c2) { kr -= c2; digit = 3; } } }
                sh_prefix = prefix | ((unsigned)(lane*4 + digit) << shift);
                sh_k = kr;
            }
        }
        __syncthreads();
        prefix = sh_prefix;
        kk = sh_k;
    }
    // prefix == exact k-th smallest key; choose = (key <= prefix)

    // ---- phase E: masked weighted average (recompute n, zero extra regs) ----
    float ex = 0.f, ey = 0.f, ez = 0.f, ew = 0.f, d2 = 0.f;
    #pragma unroll
    for (int r = 0; r < RPT; ++r) {
        float ss = q[r].x*q[r].x + q[r].y*q[r].y + q[r].z*q[r].z + q[r].w*q[r].w;
        ss += dpp_xor1(ss); ss += dpp_xor2(ss);
        float n = sqrtf(ss);
        float w = (key[r] <= prefix) ? n : 0.f;
        ex += q[r].x * w; ey += q[r].y * w; ez += q[r].z * w; ew += q[r].w * w;
        d2 += w;
    }
    #pragma unroll
    for (int off = 4; off < 64; off <<= 1) {
        ex += __shfl_down(ex, off); ey += __shfl_down(ey, off);
        ez += __shfl_down(ez, off); ew += __shfl_down(ew, off);
        d2 += __shfl_down(d2, off);
    }
    d2 += dpp_xor1(d2); d2 += dpp_xor2(d2);
    if (lane < 4) {
        float* dst = &sh_num[wave][lane * 4];
        dst[0] = ex; dst[1] = ey; dst[2] = ez; dst[3] = ew;
    }
    if (lane == 0) sh_den[wave] = d2;
    __syncthreads();
    if (t < D_DIM) {
        float nm = 0.f, dd = 0.f;
        #pragma unroll
        for (int w = 0; w < NWAVES; ++w) { nm += sh_num[w][t]; dd += sh_den[w]; }
        out[((size_t)b * O_CAPS + o) * D_DIM + t] = nm / (dd * 0.25f);
    }
}

extern "C" void kernel_launch(void* const* d_in, const int* in_sizes, int n_in,
                              void* d_out, int out_size, void* d_ws, size_t ws_size,
                              hipStream_t stream) {
    const float* u = (const float*)d_in[0];
    float* out = (float*)d_out;
    const int B = 128;
    subset_routing_kernel<<<dim3(B * O_CAPS), dim3(BLOCK), 0, stream>>>(u, out);
}

// Round 5
// 429.272 us; speedup vs baseline: 1.1413x; 1.1413x over previous
//
#include <hip/hip_runtime.h>
#include <math.h>

#define BLOCK   384
#define I_CAPS  1152
#define O_CAPS  32
#define D_DIM   16
#define RPT     12         // quarter-rows (float4 chunks) per thread
#define K_SEL   922        // ceil(0.8 * 1152)
#define NWAVES  6

// intra-quad xor shuffles as DPP (VALU pipe, not LDS)
__device__ __forceinline__ float dpp_xor1(float x) {
    return __int_as_float(__builtin_amdgcn_mov_dpp(__float_as_int(x), 0xB1, 0xF, 0xF, true));
}
__device__ __forceinline__ float dpp_xor2(float x) {
    return __int_as_float(__builtin_amdgcn_mov_dpp(__float_as_int(x), 0x4E, 0xF, 0xF, true));
}
__device__ __forceinline__ unsigned dpp_xor1_u(unsigned x) {
    return (unsigned)__builtin_amdgcn_mov_dpp((int)x, 0xB1, 0xF, 0xF, true);
}
__device__ __forceinline__ unsigned dpp_xor2_u(unsigned x) {
    return (unsigned)__builtin_amdgcn_mov_dpp((int)x, 0x4E, 0xF, 0xF, true);
}

__global__ __launch_bounds__(BLOCK, 4)
void subset_routing_kernel(const float* __restrict__ u, float* __restrict__ out) {
    __shared__ int   sh_hist[NWAVES][256];   // per-wave histograms: wave-local atomics
    __shared__ float sh_num[NWAVES][16];
    __shared__ float sh_den[NWAVES];
    __shared__ float sh_v[D_DIM];
    __shared__ unsigned sh_prefix;
    __shared__ int   sh_k;

    const int t    = threadIdx.x;
    const int lane = t & 63;
    const int wave = t >> 6;
    const int c    = t & 3;    // d-chunk (quad lane)
    const int s    = t >> 2;   // row-subgroup 0..95

    // block -> (b,o): pair (b,2j)/(b,2j+1) on same XCD so 128B lines are shared
    int X = blockIdx.x;
    int r8 = X & 7, mm = (X >> 3) & 1, q8 = X >> 4;
    int p  = q8 * 8 + r8;
    int b  = p >> 4;
    int o  = ((p & 15) << 1) | mm;

    const float* base = u + (((size_t)b * I_CAPS) * O_CAPS + (size_t)o) * D_DIM + c * 4;

    // coalesced: per wave-load, 16 rows x 64B contiguous chunks
    float4 q[RPT];
    #pragma unroll
    for (int r = 0; r < RPT; ++r)
        q[r] = *(const float4*)(base + (size_t)(r * 96 + s) * (O_CAPS * D_DIM));

    // ---- phase A: norms + weighted sums (norms via quad DPP xor) ----
    float ax = 0.f, ay = 0.f, az = 0.f, aw = 0.f, dn = 0.f;
    #pragma unroll
    for (int r = 0; r < RPT; ++r) {
        float ss = q[r].x*q[r].x + q[r].y*q[r].y + q[r].z*q[r].z + q[r].w*q[r].w;
        ss += dpp_xor1(ss); ss += dpp_xor2(ss);     // full row ||u||^2 in all 4 lanes
        float n = sqrtf(ss);
        ax += q[r].x * n; ay += q[r].y * n; az += q[r].z * n; aw += q[r].w * n;
        dn += n;                                    // counted x4 across quad; /4 later
    }
    #pragma unroll
    for (int off = 4; off < 64; off <<= 1) {        // reduce over same-c lanes
        ax += __shfl_down(ax, off); ay += __shfl_down(ay, off);
        az += __shfl_down(az, off); aw += __shfl_down(aw, off);
        dn += __shfl_down(dn, off);
    }
    dn += dpp_xor1(dn); dn += dpp_xor2(dn);         // fold quad for den
    if (lane < 4) {
        float* dst = &sh_num[wave][lane * 4];
        dst[0] = ax; dst[1] = ay; dst[2] = az; dst[3] = aw;
    }
    if (lane == 0) sh_den[wave] = dn;
    __syncthreads();
    if (t < D_DIM) {
        float nm = 0.f, dd = 0.f;
        #pragma unroll
        for (int w = 0; w < NWAVES; ++w) { nm += sh_num[w][t]; dd += sh_den[w]; }
        sh_v[t] = nm / (dd * 0.25f);
    }
    __syncthreads();
    float4 v4 = make_float4(sh_v[c*4+0], sh_v[c*4+1], sh_v[c*4+2], sh_v[c*4+3]);

    // ---- keys: loss = -<v,u_i> -> order-preserving uint; keep ONLY the 3 owned
    // (quad lane c owns rows [3c, 3c+3)) to hold register pressure down ----
    unsigned mk[3];
    #pragma unroll
    for (int r = 0; r < RPT; ++r) {
        float dl = v4.x*q[r].x + v4.y*q[r].y + v4.z*q[r].z + v4.w*q[r].w;
        dl += dpp_xor1(dl); dl += dpp_xor2(dl);
        unsigned bits = __float_as_uint(-dl);
        unsigned kv = bits ^ (((unsigned)((int)bits >> 31)) | 0x80000000u);
        if (r / 3 == c) mk[r % 3] = kv;   // r/3, r%3 are compile-time
    }
    int* myhist = sh_hist[wave];

    // ---- exact k-th smallest: 4-round MSD radix select, per-wave hists ----
    unsigned prefix = 0u;
    int kk = K_SEL;
    #pragma unroll
    for (int shift = 24; shift >= 0; shift -= 8) {
        // wave-local zero (no cross-wave dependency -> no barrier needed here)
        *(int4*)&myhist[lane * 4] = make_int4(0, 0, 0, 0);
        unsigned maskAbove = (shift == 24) ? 0u : (0xFFFFFFFFu << (shift + 8));
        if ((mk[0] & maskAbove) == prefix) atomicAdd(&myhist[(mk[0] >> shift) & 255u], 1);
        if ((mk[1] & maskAbove) == prefix) atomicAdd(&myhist[(mk[1] >> shift) & 255u], 1);
        if ((mk[2] & maskAbove) == prefix) atomicAdd(&myhist[(mk[2] >> shift) & 255u], 1);
        __syncthreads();
        if (wave == 0) {
            int c0 = 0, c1 = 0, c2 = 0, c3 = 0;
            #pragma unroll
            for (int w = 0; w < NWAVES; ++w) {
                int4 h = *(int4*)&sh_hist[w][lane * 4];
                c0 += h.x; c1 += h.y; c2 += h.z; c3 += h.w;
            }
            int sm = c0 + c1 + c2 + c3;
            int cum = sm;
            #pragma unroll
            for (int off = 1; off < 64; off <<= 1) {
                int vsh = __shfl_up(cum, off);
                if (lane >= off) cum += vsh;
            }
            int cumprev = cum - sm;
            bool has = (cumprev < kk) && (cum >= kk);
            unsigned long long ball = __ballot(has);
            int win = __ffsll(ball) - 1;
            if (lane == win) {
                int kr = kk - cumprev;
                int digit = 0;
                if (kr > c0) { kr -= c0; digit = 1;
                    if (kr > c1) { kr -= c1; digit = 2;
                        if (kr > c2) { kr -= c2; digit = 3; } } }
                sh_prefix = prefix | ((unsigned)(lane*4 + digit) << shift);
                sh_k = kr;
            }
        }
        __syncthreads();
        prefix = sh_prefix;
        kk = sh_k;
    }
    // prefix == exact k-th smallest key; choose = (key <= prefix)

    // broadcast choose-bits across the quad: lane c contributes bits [3c,3c+3)
    unsigned cmask = ((mk[0] <= prefix) ? 1u : 0u)
                   | ((mk[1] <= prefix) ? 2u : 0u)
                   | ((mk[2] <= prefix) ? 4u : 0u);
    cmask <<= (3 * c);
    cmask |= dpp_xor1_u(cmask);
    cmask |= dpp_xor2_u(cmask);   // all 4 quad lanes now hold all 12 bits

    // ---- phase E: masked weighted average (recompute n, zero extra regs) ----
    float ex = 0.f, ey = 0.f, ez = 0.f, ew = 0.f, d2 = 0.f;
    #pragma unroll
    for (int r = 0; r < RPT; ++r) {
        float ss = q[r].x*q[r].x + q[r].y*q[r].y + q[r].z*q[r].z + q[r].w*q[r].w;
        ss += dpp_xor1(ss); ss += dpp_xor2(ss);
        float n = sqrtf(ss);
        float w = ((cmask >> r) & 1u) ? n : 0.f;
        ex += q[r].x * w; ey += q[r].y * w; ez += q[r].z * w; ew += q[r].w * w;
        d2 += w;
    }
    #pragma unroll
    for (int off = 4; off < 64; off <<= 1) {
        ex += __shfl_down(ex, off); ey += __shfl_down(ey, off);
        ez += __shfl_down(ez, off); ew += __shfl_down(ew, off);
        d2 += __shfl_down(d2, off);
    }
    d2 += dpp_xor1(d2); d2 += dpp_xor2(d2);
    if (lane < 4) {
        float* dst = &sh_num[wave][lane * 4];
        dst[0] = ex; dst[1] = ey; dst[2] = ez; dst[3] = ew;
    }
    if (lane == 0) sh_den[wave] = d2;
    __syncthreads();
    if (t < D_DIM) {
        float nm = 0.f, dd = 0.f;
        #pragma unroll
        for (int w = 0; w < NWAVES; ++w) { nm += sh_num[w][t]; dd += sh_den[w]; }
        out[((size_t)b * O_CAPS + o) * D_DIM + t] = nm / (dd * 0.25f);
    }
}

extern "C" void kernel_launch(void* const* d_in, const int* in_sizes, int n_in,
                              void* d_out, int out_size, void* d_ws, size_t ws_size,
                              hipStream_t stream) {
    const float* u = (const float*)d_in[0];
    float* out = (float*)d_out;
    const int B = 128;
    subset_routing_kernel<<<dim3(B * O_CAPS), dim3(BLOCK), 0, stream>>>(u, out);
}

// Round 7
// 411.083 us; speedup vs baseline: 1.1918x; 1.0442x over previous
//
#include <hip/hip_runtime.h>
#include <math.h>

#define BLOCK   384
#define I_CAPS  1152
#define O_CAPS  32
#define D_DIM   16
#define RPT     12         // quarter-rows (float4 chunks) per thread
#define K_SEL   922        // ceil(0.8 * 1152)
#define NWAVES  6

// intra-quad xor shuffles as DPP (VALU pipe, not LDS)
__device__ __forceinline__ float dpp_xor1(float x) {
    return __int_as_float(__builtin_amdgcn_mov_dpp(__float_as_int(x), 0xB1, 0xF, 0xF, true));
}
__device__ __forceinline__ float dpp_xor2(float x) {
    return __int_as_float(__builtin_amdgcn_mov_dpp(__float_as_int(x), 0x4E, 0xF, 0xF, true));
}
__device__ __forceinline__ unsigned dpp_xor1_u(unsigned x) {
    return (unsigned)__builtin_amdgcn_mov_dpp((int)x, 0xB1, 0xF, 0xF, true);
}
__device__ __forceinline__ unsigned dpp_xor2_u(unsigned x) {
    return (unsigned)__builtin_amdgcn_mov_dpp((int)x, 0x4E, 0xF, 0xF, true);
}

__global__ __launch_bounds__(BLOCK, 4)
void subset_routing_kernel(const float* __restrict__ u, float* __restrict__ out) {
    __shared__ int   sh_hist[NWAVES][256];   // per-wave histograms: wave-local atomics
    __shared__ float sh_num[NWAVES][16];
    __shared__ float sh_den[NWAVES];
    __shared__ float sh_v[D_DIM];
    __shared__ unsigned sh_prefix;
    __shared__ int   sh_k;

    const int t    = threadIdx.x;
    const int lane = t & 63;
    const int wave = t >> 6;
    const int c    = t & 3;    // d-chunk (quad lane)
    const int s    = t >> 2;   // row-subgroup 0..95

    // XCD-affinity swizzle: X = (b>>3)*256 + o*8 + (b&7), so X mod 8 (the
    // XCD round-robin) is constant for all 32 o-blocks of a given b. Their
    // 2KB rows interleave inside one XCD's L2: (o,o+1) share 128B L2 lines
    // (hit ~200cyc instead of ~900 HBM) and the XCD's combined miss stream
    // covers whole 2KB spans -> DRAM page locality for the misses.
    int X = blockIdx.x;
    int b = ((X >> 8) << 3) | (X & 7);   // [0,128)
    int o = (X >> 3) & 31;               // [0,32)

    const float* base = u + (((size_t)b * I_CAPS) * O_CAPS + (size_t)o) * D_DIM + c * 4;

    // coalesced: per wave-load, 16 rows x 64B contiguous chunks
    float4 q[RPT];
    #pragma unroll
    for (int r = 0; r < RPT; ++r)
        q[r] = *(const float4*)(base + (size_t)(r * 96 + s) * (O_CAPS * D_DIM));

    // ---- phase A: norms + weighted sums (norms via quad DPP xor) ----
    float ax = 0.f, ay = 0.f, az = 0.f, aw = 0.f, dn = 0.f;
    #pragma unroll
    for (int r = 0; r < RPT; ++r) {
        float ss = q[r].x*q[r].x + q[r].y*q[r].y + q[r].z*q[r].z + q[r].w*q[r].w;
        ss += dpp_xor1(ss); ss += dpp_xor2(ss);     // full row ||u||^2 in all 4 lanes
        float n = sqrtf(ss);
        ax += q[r].x * n; ay += q[r].y * n; az += q[r].z * n; aw += q[r].w * n;
        dn += n;                                    // counted x4 across quad; /4 later
    }
    #pragma unroll
    for (int off = 4; off < 64; off <<= 1) {        // reduce over same-c lanes
        ax += __shfl_down(ax, off); ay += __shfl_down(ay, off);
        az += __shfl_down(az, off); aw += __shfl_down(aw, off);
        dn += __shfl_down(dn, off);
    }
    dn += dpp_xor1(dn); dn += dpp_xor2(dn);         // fold quad for den
    if (lane < 4) {
        float* dst = &sh_num[wave][lane * 4];
        dst[0] = ax; dst[1] = ay; dst[2] = az; dst[3] = aw;
    }
    if (lane == 0) sh_den[wave] = dn;
    __syncthreads();
    if (t < D_DIM) {
        float nm = 0.f, dd = 0.f;
        #pragma unroll
        for (int w = 0; w < NWAVES; ++w) { nm += sh_num[w][t]; dd += sh_den[w]; }
        sh_v[t] = nm / (dd * 0.25f);
    }
    __syncthreads();
    float4 v4 = make_float4(sh_v[c*4+0], sh_v[c*4+1], sh_v[c*4+2], sh_v[c*4+3]);

    // ---- keys: loss = -<v,u_i> -> order-preserving uint; keep ONLY the 3 owned
    // (quad lane c owns rows [3c, 3c+3)) to hold register pressure down ----
    unsigned mk[3];
    #pragma unroll
    for (int r = 0; r < RPT; ++r) {
        float dl = v4.x*q[r].x + v4.y*q[r].y + v4.z*q[r].z + v4.w*q[r].w;
        dl += dpp_xor1(dl); dl += dpp_xor2(dl);
        unsigned bits = __float_as_uint(-dl);
        unsigned kv = bits ^ (((unsigned)((int)bits >> 31)) | 0x80000000u);
        if (r / 3 == c) mk[r % 3] = kv;   // r/3, r%3 are compile-time
    }
    int* myhist = sh_hist[wave];

    // ---- exact k-th smallest: 4-round MSD radix select, per-wave hists ----
    unsigned prefix = 0u;
    int kk = K_SEL;
    #pragma unroll
    for (int shift = 24; shift >= 0; shift -= 8) {
        // wave-local zero (no cross-wave dependency -> no barrier needed here)
        *(int4*)&myhist[lane * 4] = make_int4(0, 0, 0, 0);
        unsigned maskAbove = (shift == 24) ? 0u : (0xFFFFFFFFu << (shift + 8));
        if ((mk[0] & maskAbove) == prefix) atomicAdd(&myhist[(mk[0] >> shift) & 255u], 1);
        if ((mk[1] & maskAbove) == prefix) atomicAdd(&myhist[(mk[1] >> shift) & 255u], 1);
        if ((mk[2] & maskAbove) == prefix) atomicAdd(&myhist[(mk[2] >> shift) & 255u], 1);
        __syncthreads();
        if (wave == 0) {
            int c0 = 0, c1 = 0, c2 = 0, c3 = 0;
            #pragma unroll
            for (int w = 0; w < NWAVES; ++w) {
                int4 h = *(int4*)&sh_hist[w][lane * 4];
                c0 += h.x; c1 += h.y; c2 += h.z; c3 += h.w;
            }
            int sm = c0 + c1 + c2 + c3;
            int cum = sm;
            #pragma unroll
            for (int off = 1; off < 64; off <<= 1) {
                int vsh = __shfl_up(cum, off);
                if (lane >= off) cum += vsh;
            }
            int cumprev = cum - sm;
            bool has = (cumprev < kk) && (cum >= kk);
            unsigned long long ball = __ballot(has);
            int win = __ffsll(ball) - 1;
            if (lane == win) {
                int kr = kk - cumprev;
                int digit = 0;
                if (kr > c0) { kr -= c0; digit = 1;
                    if (kr > c1) { kr -= c1; digit = 2;
                        if (kr > c2) { kr -= c2; digit = 3; } } }
                sh_prefix = prefix | ((unsigned)(lane*4 + digit) << shift);
                sh_k = kr;
            }
        }
        __syncthreads();
        prefix = sh_prefix;
        kk = sh_k;
    }
    // prefix == exact k-th smallest key; choose = (key <= prefix)

    // broadcast choose-bits across the quad: lane c contributes bits [3c,3c+3)
    unsigned cmask = ((mk[0] <= prefix) ? 1u : 0u)
                   | ((mk[1] <= prefix) ? 2u : 0u)
                   | ((mk[2] <= prefix) ? 4u : 0u);
    cmask <<= (3 * c);
    cmask |= dpp_xor1_u(cmask);
    cmask |= dpp_xor2_u(cmask);   // all 4 quad lanes now hold all 12 bits

    // ---- phase E: masked weighted average (recompute n, zero extra regs) ----
    float ex = 0.f, ey = 0.f, ez = 0.f, ew = 0.f, d2 = 0.f;
    #pragma unroll
    for (int r = 0; r < RPT; ++r) {
        float ss = q[r].x*q[r].x + q[r].y*q[r].y + q[r].z*q[r].z + q[r].w*q[r].w;
        ss += dpp_xor1(ss); ss += dpp_xor2(ss);
        float n = sqrtf(ss);
        float w = ((cmask >> r) & 1u) ? n : 0.f;
        ex += q[r].x * w; ey += q[r].y * w; ez += q[r].z * w; ew += q[r].w * w;
        d2 += w;
    }
    #pragma unroll
    for (int off = 4; off < 64; off <<= 1) {
        ex += __shfl_down(ex, off); ey += __shfl_down(ey, off);
        ez += __shfl_down(ez, off); ew += __shfl_down(ew, off);
        d2 += __shfl_down(d2, off);
    }
    d2 += dpp_xor1(d2); d2 += dpp_xor2(d2);
    if (lane < 4) {
        float* dst = &sh_num[wave][lane * 4];
        dst[0] = ex; dst[1] = ey; dst[2] = ez; dst[3] = ew;
    }
    if (lane == 0) sh_den[wave] = d2;
    __syncthreads();
    if (t < D_DIM) {
        float nm = 0.f, dd = 0.f;
        #pragma unroll
        for (int w = 0; w < NWAVES; ++w) { nm += sh_num[w][t]; dd += sh_den[w]; }
        out[((size_t)b * O_CAPS + o) * D_DIM + t] = nm / (dd * 0.25f);
    }
}

extern "C" void kernel_launch(void* const* d_in, const int* in_sizes, int n_in,
                              void* d_out, int out_size, void* d_ws, size_t ws_size,
                              hipStream_t stream) {
    const float* u = (const float*)d_in[0];
    float* out = (float*)d_out;
    const int B = 128;
    subset_routing_kernel<<<dim3(B * O_CAPS), dim3(BLOCK), 0, stream>>>(u, out);
}